// Round 1
// baseline (116.519 us; speedup 1.0000x reference)
//
#include <hip/hip_runtime.h>

// Problem constants (from reference): M=8 samples, N=4096, K=16 filters.
#define NN 4096
#define MM 8
#define KK 16

// Kernel 1: col[m] = sum_j L[j, m]  (column sums of row-major L[N][N]).
// Grid: (NN/256 = 16 column blocks, 32 row blocks). Each thread owns one
// column within its block, accumulates 128 rows in a register, then one
// atomicAdd. Reads are coalesced (consecutive tid -> consecutive addresses).
__global__ void __launch_bounds__(256) colsum_kernel(const float* __restrict__ L,
                                                     float* __restrict__ col) {
    const int m  = blockIdx.x * 256 + threadIdx.x;
    const int r0 = blockIdx.y * 128;
    float acc = 0.f;
#pragma unroll 8
    for (int j = 0; j < 128; ++j) {
        acc += L[(size_t)(r0 + j) * NN + m];
    }
    atomicAdd(&col[m], acc);  // device-scope by default; 32 adds per address total
}

// Kernel 2: per output row (b,i):
//   s = dot(x[b,i,:], col);  out[b,i] = sum_k tanh(W[k,i] * s)
// One 64-lane wave per row; 4 waves (256 threads) per block; 8192 blocks.
// Each lane: 16 float4 loads of x (wave reads contiguous 1KB per iter,
// fully coalesced); col is 16KB and L1/L2-resident after first touch.
__global__ void __launch_bounds__(256) conv_kernel(const float* __restrict__ x,
                                                   const float* __restrict__ col,
                                                   const float* __restrict__ W,
                                                   float* __restrict__ out) {
    const int wave = threadIdx.x >> 6;         // 0..3
    const int lane = threadIdx.x & 63;
    const int row  = blockIdx.x * 4 + wave;    // 0 .. 32767  (= b*NN + i)
    const int i    = row & (NN - 1);

    const float4* __restrict__ xr = reinterpret_cast<const float4*>(x) + (size_t)row * (NN / 4);
    const float4* __restrict__ cv = reinterpret_cast<const float4*>(col);

    float acc = 0.f;
#pragma unroll
    for (int it = 0; it < NN / 4 / 64; ++it) {      // 16 iterations
        const float4 a = xr[it * 64 + lane];
        const float4 c = cv[it * 64 + lane];
        acc += a.x * c.x + a.y * c.y + a.z * c.z + a.w * c.w;
    }

    // Butterfly reduce: every lane ends with the full dot product s.
#pragma unroll
    for (int off = 32; off >= 1; off >>= 1)
        acc += __shfl_xor(acc, off, 64);

    // Lanes 0..15 each evaluate one filter; lanes 16..63 contribute 0.
    float r = 0.f;
    if (lane < KK) r = tanhf(W[lane * NN + i] * acc);
#pragma unroll
    for (int off = 8; off >= 1; off >>= 1)
        r += __shfl_down(r, off, 64);

    if (lane == 0) out[row] = r;
}

extern "C" void kernel_launch(void* const* d_in, const int* in_sizes, int n_in,
                              void* d_out, int out_size, void* d_ws, size_t ws_size,
                              hipStream_t stream) {
    const float* x = (const float*)d_in[0];  // [M, N, N]
    const float* L = (const float*)d_in[1];  // [N, N]
    const float* W = (const float*)d_in[2];  // [K, N]
    float* out = (float*)d_out;              // [M, N] fp32
    float* col = (float*)d_ws;               // [N] scratch

    // col must be zeroed every call (ws is poisoned once, never re-poisoned).
    hipMemsetAsync(col, 0, NN * sizeof(float), stream);

    colsum_kernel<<<dim3(NN / 256, 32), 256, 0, stream>>>(L, col);
    conv_kernel<<<(MM * NN) / 4, 256, 0, stream>>>(x, col, W, out);
}